// Round 1
// baseline (3497.978 us; speedup 1.0000x reference)
//
#include <hip/hip_runtime.h>
#include <hip/hip_bf16.h>

// Problem shape (from setup_inputs): B=32, L=1024, D=64, T=target_length=1024.
// out[t,b,j] = softmax_j( enc[b,t,:] . (W @ enc[b,j,:] + bias) ), diag(t==j) score forced to 0 pre-softmax.
constexpr int Bn = 32;
constexpr int Ln = 1024;
constexpr int Dn = 64;
constexpr int TT = 16;   // t-rows per block (kernel2)
constexpr int JJ = 256;  // j-tile per LDS stage (kernel2)

// ---------------- Kernel 1: energy[b,l,e] = bias[e] + sum_d enc[b,l,d]*W[e,d] ----------------
// grid (L/4, B), block 256 = 4 l-rows x 64 e. W staged in LDS with float4-chunk XOR swizzle.
__global__ __launch_bounds__(256, 4) void energy_kernel(
    const float* __restrict__ enc, const float* __restrict__ W,
    const float* __restrict__ bias, float* __restrict__ energy) {
  __shared__ float Ws[64 * 64];   // rows e, 16 float4 chunks each, chunk index XOR (e&15)
  __shared__ float encs[4 * 64];  // 4 l-rows, linear

  const int tid = threadIdx.x;
  const int b = blockIdx.y;
  const int l0 = blockIdx.x * 4;

  // stage W (1024 float4s, 4 per thread), swizzled
  const float4* Wsrc = reinterpret_cast<const float4*>(W);
#pragma unroll
  for (int s = 0; s < 4; ++s) {
    int f = tid + s * 256;
    int e = f >> 4, d4 = f & 15;
    reinterpret_cast<float4*>(Ws)[e * 16 + (d4 ^ (e & 15))] = Wsrc[f];
  }
  // stage 4 enc rows (64 float4s)
  if (tid < 64) {
    reinterpret_cast<float4*>(encs)[tid] =
        reinterpret_cast<const float4*>(enc + ((size_t)b * Ln + l0) * Dn)[tid];
  }
  __syncthreads();

  const int lr = tid >> 6;   // which l row (wave id)
  const int e = tid & 63;    // output feature
  const int x = e & 15;
  float acc = bias[e];
#pragma unroll
  for (int d4 = 0; d4 < 16; ++d4) {
    float4 wv = reinterpret_cast<const float4*>(Ws)[e * 16 + (d4 ^ x)];
    float4 ev = reinterpret_cast<const float4*>(encs)[lr * 16 + d4];  // broadcast
    acc += wv.x * ev.x + wv.y * ev.y + wv.z * ev.z + wv.w * ev.w;
  }
  energy[((size_t)b * Ln + l0 + lr) * Dn + e] = acc;
}

// ---------------- Kernel 2: scores + diag-zero + softmax + write ----------------
// grid (T/TT, B), block 256. Wave ty owns rows t0+ty*4 .. t0+ty*4+3 (each row = 64 lanes x 16 j).
// Thread (ty,jx) computes acc[r=0..3][q=0..15] for t = t0+ty*4+r, j = (q>>2)*256 + jx*4 + (q&3).
__global__ __launch_bounds__(256, 2) void scores_kernel(
    const float* __restrict__ enc, const float* __restrict__ energy,
    float* __restrict__ out, int Tval) {
  __shared__ float enc_s[TT * Dn];   // 4 KB, linear (reads are wave-broadcast)
  __shared__ float eng_s[JJ * Dn];   // 64 KB, float4-chunk XOR-swizzled by (row>>2)&15

  const int tid = threadIdx.x;
  const int b = blockIdx.y;
  const int t0 = blockIdx.x * TT;
  const int ty = tid >> 6;   // wave id 0..3
  const int jx = tid & 63;
  const int x = jx & 15;     // read-side XOR key: ((jx*4+c)>>2)&15 == jx&15

  // stage enc t-tile: 256 float4s
  reinterpret_cast<float4*>(enc_s)[tid] =
      reinterpret_cast<const float4*>(enc + ((size_t)b * Ln + t0) * Dn)[tid];

  float acc[4][16];
#pragma unroll
  for (int r = 0; r < 4; ++r)
#pragma unroll
    for (int q = 0; q < 16; ++q) acc[r][q] = 0.f;

#pragma unroll
  for (int jt = 0; jt < 4; ++jt) {
    __syncthreads();  // previous tile fully read (and enc_s written before first compute)
    // stage energy j-tile (4096 float4s, 16 per thread), swizzled
    const float4* src =
        reinterpret_cast<const float4*>(energy + ((size_t)b * Ln + jt * JJ) * Dn);
#pragma unroll
    for (int s = 0; s < 16; ++s) {
      int f = tid + s * 256;
      int row = f >> 4, d4 = f & 15;
      float4 v = src[f];
      reinterpret_cast<float4*>(eng_s)[row * 16 + (d4 ^ ((row >> 2) & 15))] = v;
    }
    __syncthreads();

#pragma unroll
    for (int d4 = 0; d4 < 16; ++d4) {
      const int d4p = d4 ^ x;
      float4 e0 = reinterpret_cast<const float4*>(enc_s)[(ty * 4 + 0) * 16 + d4];
      float4 e1 = reinterpret_cast<const float4*>(enc_s)[(ty * 4 + 1) * 16 + d4];
      float4 e2 = reinterpret_cast<const float4*>(enc_s)[(ty * 4 + 2) * 16 + d4];
      float4 e3 = reinterpret_cast<const float4*>(enc_s)[(ty * 4 + 3) * 16 + d4];
      float4 g0 = reinterpret_cast<const float4*>(eng_s)[(jx * 4 + 0) * 16 + d4p];
      float4 g1 = reinterpret_cast<const float4*>(eng_s)[(jx * 4 + 1) * 16 + d4p];
      float4 g2 = reinterpret_cast<const float4*>(eng_s)[(jx * 4 + 2) * 16 + d4p];
      float4 g3 = reinterpret_cast<const float4*>(eng_s)[(jx * 4 + 3) * 16 + d4p];
#pragma unroll
      for (int r = 0; r < 4; ++r) {
        float4 er = (r == 0) ? e0 : (r == 1) ? e1 : (r == 2) ? e2 : e3;
        acc[r][jt * 4 + 0] += er.x * g0.x + er.y * g0.y + er.z * g0.z + er.w * g0.w;
        acc[r][jt * 4 + 1] += er.x * g1.x + er.y * g1.y + er.z * g1.z + er.w * g1.w;
        acc[r][jt * 4 + 2] += er.x * g2.x + er.y * g2.y + er.z * g2.z + er.w * g2.w;
        acc[r][jt * 4 + 3] += er.x * g3.x + er.y * g3.y + er.z * g3.z + er.w * g3.w;
      }
    }
  }

  // epilogue: diag zero, row softmax (row == one wave), fused write
#pragma unroll
  for (int r = 0; r < 4; ++r) {
    const int t_g = t0 + ty * 4 + r;
    if (t_g >= Tval) continue;  // wave-uniform
#pragma unroll
    for (int q = 0; q < 16; ++q) {
      int j_g = (q >> 2) * 256 + jx * 4 + (q & 3);
      if (j_g == t_g) acc[r][q] = 0.f;
    }
    float m = acc[r][0];
#pragma unroll
    for (int q = 1; q < 16; ++q) m = fmaxf(m, acc[r][q]);
#pragma unroll
    for (int off = 32; off > 0; off >>= 1) m = fmaxf(m, __shfl_xor(m, off));
    float s = 0.f;
#pragma unroll
    for (int q = 0; q < 16; ++q) {
      float e = __expf(acc[r][q] - m);
      acc[r][q] = e;
      s += e;
    }
#pragma unroll
    for (int off = 32; off > 0; off >>= 1) s += __shfl_xor(s, off);
    const float inv = 1.0f / s;
    float* orow = out + ((size_t)t_g * Bn + b) * Ln;
#pragma unroll
    for (int jt = 0; jt < 4; ++jt) {
      float4 v;
      v.x = acc[r][jt * 4 + 0] * inv;
      v.y = acc[r][jt * 4 + 1] * inv;
      v.z = acc[r][jt * 4 + 2] * inv;
      v.w = acc[r][jt * 4 + 3] * inv;
      *reinterpret_cast<float4*>(orow + jt * 256 + jx * 4) = v;
    }
  }
}

extern "C" void kernel_launch(void* const* d_in, const int* in_sizes, int n_in,
                              void* d_out, int out_size, void* d_ws, size_t ws_size,
                              hipStream_t stream) {
  const float* enc = (const float*)d_in[0];
  const float* W = (const float*)d_in[1];
  const float* bias = (const float*)d_in[2];
  float* out = (float*)d_out;
  float* energy = (float*)d_ws;  // B*L*D floats = 8 MB

  const int Tval = out_size / (Bn * Ln);  // 1024 in this problem

  energy_kernel<<<dim3(Ln / 4, Bn), 256, 0, stream>>>(enc, W, bias, energy);
  scores_kernel<<<dim3((Tval + TT - 1) / TT, Bn), 256, 0, stream>>>(enc, energy, out, Tval);
}

// Round 4
// 3482.241 us; speedup vs baseline: 1.0045x; 1.0045x over previous
//
#include <hip/hip_runtime.h>
#include <hip/hip_bf16.h>

// B=32, L=1024, D=64, T=1024.
// out[t,b,j] = softmax_j( enc[b,t,:] . energy[b,j,:] ), energy = enc@W^T + bias,
// diagonal (j==t) score forced to 0 before softmax.
constexpr int Bn = 32;
constexpr int Ln = 1024;
constexpr int Dn = 64;
constexpr int TT = 16;   // t-rows per block (kernel2)
constexpr int JJ = 256;  // j-tile per LDS stage (kernel2)

// ---------------- Kernel 1: energy[b,l,e] = bias[e] + sum_d enc[b,l,d]*W[e,d] ----------------
__global__ __launch_bounds__(256, 4) void energy_kernel(
    const float* __restrict__ enc, const float* __restrict__ W,
    const float* __restrict__ bias, float* __restrict__ energy) {
  __shared__ float Ws[64 * 64];   // rows e, 16 float4 chunks each, chunk idx XOR (e&15)
  __shared__ float encs[4 * 64];

  const int tid = threadIdx.x;
  const int b = blockIdx.y;
  const int l0 = blockIdx.x * 4;

  const float4* Wsrc = reinterpret_cast<const float4*>(W);
#pragma unroll
  for (int s = 0; s < 4; ++s) {
    int f = tid + s * 256;
    int e = f >> 4, d4 = f & 15;
    reinterpret_cast<float4*>(Ws)[e * 16 + (d4 ^ (e & 15))] = Wsrc[f];
  }
  if (tid < 64) {
    reinterpret_cast<float4*>(encs)[tid] =
        reinterpret_cast<const float4*>(enc + ((size_t)b * Ln + l0) * Dn)[tid];
  }
  __syncthreads();

  const int lr = tid >> 6;
  const int e = tid & 63;
  const int x = e & 15;
  float acc = bias[e];
#pragma unroll
  for (int d4 = 0; d4 < 16; ++d4) {
    float4 wv = reinterpret_cast<const float4*>(Ws)[e * 16 + (d4 ^ x)];
    float4 ev = reinterpret_cast<const float4*>(encs)[lr * 16 + d4];
    acc += wv.x * ev.x + wv.y * ev.y + wv.z * ev.z + wv.w * ev.w;
  }
  energy[((size_t)b * Ln + l0 + lr) * Dn + e] = acc;
}

// ---------------- Kernel 2 helpers ----------------
__device__ __forceinline__ float dot4(float4 a, float4 b) {
  return a.x * b.x + a.y * b.y + a.z * b.z + a.w * b.w;
}
__device__ __forceinline__ void diagzero(float4& a, int jbase, int t_g) {
  if (jbase + 0 == t_g) a.x = 0.f;
  if (jbase + 1 == t_g) a.y = 0.f;
  if (jbase + 2 == t_g) a.z = 0.f;
  if (jbase + 3 == t_g) a.w = 0.f;
}
__device__ __forceinline__ float max4(float4 a) {
  return fmaxf(fmaxf(a.x, a.y), fmaxf(a.z, a.w));
}
__device__ __forceinline__ float exp4(float4& a, float m) {
  a.x = __expf(a.x - m); a.y = __expf(a.y - m);
  a.z = __expf(a.z - m); a.w = __expf(a.w - m);
  return (a.x + a.y) + (a.z + a.w);
}
__device__ __forceinline__ void store4(float* p, float4 a, float inv) {
  float4 v;
  v.x = a.x * inv; v.y = a.y * inv; v.z = a.z * inv; v.w = a.w * inv;
  *reinterpret_cast<float4*>(p) = v;
}

// ---------------- Kernel 2: scores + diag-zero + softmax + write ----------------
// grid (T/TT, B), block 256 = 4 waves. Wave ty owns t-rows t0+ty*4 .. +3.
// Thread (ty,jx): row r, tile JT, component c -> t = t0+ty*4+r, j = JT*256 + jx*4 + c.
// Accumulators are 16 NAMED float4s (aR_T) -> guaranteed VGPR residency (no dynamic idx).
__global__ __launch_bounds__(256, 2) void scores_kernel(
    const float* __restrict__ enc, const float* __restrict__ energy,
    float* __restrict__ out, int Tval) {
  __shared__ float enc_s[TT * Dn];   // 4 KB, linear (wave-broadcast reads)
  __shared__ float eng_s[JJ * Dn];   // 64 KB, float4-chunk XOR-swizzled by (row>>2)&15

  const int tid = threadIdx.x;
  const int b = blockIdx.y;
  const int t0 = blockIdx.x * TT;
  const int ty = tid >> 6;
  const int jx = tid & 63;
  const int x = jx & 15;

  reinterpret_cast<float4*>(enc_s)[tid] =
      reinterpret_cast<const float4*>(enc + ((size_t)b * Ln + t0) * Dn)[tid];

  float4 a0_0{0,0,0,0}, a0_1{0,0,0,0}, a0_2{0,0,0,0}, a0_3{0,0,0,0};
  float4 a1_0{0,0,0,0}, a1_1{0,0,0,0}, a1_2{0,0,0,0}, a1_3{0,0,0,0};
  float4 a2_0{0,0,0,0}, a2_1{0,0,0,0}, a2_2{0,0,0,0}, a2_3{0,0,0,0};
  float4 a3_0{0,0,0,0}, a3_1{0,0,0,0}, a3_2{0,0,0,0}, a3_3{0,0,0,0};

  const float4* ESF4 = reinterpret_cast<const float4*>(eng_s);
  const float4* ENF4 = reinterpret_cast<const float4*>(enc_s);

#define DO_TILE(JT)                                                              \
  {                                                                              \
    __syncthreads();                                                             \
    const float4* src = reinterpret_cast<const float4*>(                         \
        energy + ((size_t)b * Ln + (JT) * JJ) * Dn);                             \
    _Pragma("unroll") for (int s = 0; s < 16; ++s) {                             \
      int f = tid + s * 256;                                                     \
      int row = f >> 4, d4c = f & 15;                                            \
      reinterpret_cast<float4*>(eng_s)[row * 16 + (d4c ^ ((row >> 2) & 15))] =   \
          src[f];                                                                \
    }                                                                            \
    __syncthreads();                                                             \
    _Pragma("unroll") for (int d4 = 0; d4 < 16; ++d4) {                          \
      const int d4p = d4 ^ x;                                                    \
      float4 g0 = ESF4[(jx * 4 + 0) * 16 + d4p];                                 \
      float4 g1 = ESF4[(jx * 4 + 1) * 16 + d4p];                                 \
      float4 g2 = ESF4[(jx * 4 + 2) * 16 + d4p];                                 \
      float4 g3 = ESF4[(jx * 4 + 3) * 16 + d4p];                                 \
      float4 e0 = ENF4[(ty * 4 + 0) * 16 + d4];                                  \
      float4 e1 = ENF4[(ty * 4 + 1) * 16 + d4];                                  \
      float4 e2 = ENF4[(ty * 4 + 2) * 16 + d4];                                  \
      float4 e3 = ENF4[(ty * 4 + 3) * 16 + d4];                                  \
      a0_##JT.x += dot4(e0, g0); a0_##JT.y += dot4(e0, g1);                      \
      a0_##JT.z += dot4(e0, g2); a0_##JT.w += dot4(e0, g3);                      \
      a1_##JT.x += dot4(e1, g0); a1_##JT.y += dot4(e1, g1);                      \
      a1_##JT.z += dot4(e1, g2); a1_##JT.w += dot4(e1, g3);                      \
      a2_##JT.x += dot4(e2, g0); a2_##JT.y += dot4(e2, g1);                      \
      a2_##JT.z += dot4(e2, g2); a2_##JT.w += dot4(e2, g3);                      \
      a3_##JT.x += dot4(e3, g0); a3_##JT.y += dot4(e3, g1);                      \
      a3_##JT.z += dot4(e3, g2); a3_##JT.w += dot4(e3, g3);                      \
    }                                                                            \
  }

  DO_TILE(0)
  DO_TILE(1)
  DO_TILE(2)
  DO_TILE(3)
#undef DO_TILE

  // epilogue: per t-row (one wave owns the whole row): diag-zero, softmax, store.
#define ROW_EPILOGUE(R)                                                          \
  {                                                                              \
    const int t_g = t0 + ty * 4 + (R);                                           \
    if (t_g < Tval) {                                                            \
      diagzero(a##R##_0, 0 * 256 + jx * 4, t_g);                                 \
      diagzero(a##R##_1, 1 * 256 + jx * 4, t_g);                                 \
      diagzero(a##R##_2, 2 * 256 + jx * 4, t_g);                                 \
      diagzero(a##R##_3, 3 * 256 + jx * 4, t_g);                                 \
      float m = fmaxf(fmaxf(max4(a##R##_0), max4(a##R##_1)),                     \
                      fmaxf(max4(a##R##_2), max4(a##R##_3)));                    \
      m = fmaxf(m, __shfl_xor(m, 32));                                           \
      m = fmaxf(m, __shfl_xor(m, 16));                                           \
      m = fmaxf(m, __shfl_xor(m, 8));                                            \
      m = fmaxf(m, __shfl_xor(m, 4));                                            \
      m = fmaxf(m, __shfl_xor(m, 2));                                            \
      m = fmaxf(m, __shfl_xor(m, 1));                                            \
      float s = exp4(a##R##_0, m) + exp4(a##R##_1, m) +                          \
                exp4(a##R##_2, m) + exp4(a##R##_3, m);                           \
      s += __shfl_xor(s, 32);                                                    \
      s += __shfl_xor(s, 16);                                                    \
      s += __shfl_xor(s, 8);                                                     \
      s += __shfl_xor(s, 4);                                                     \
      s += __shfl_xor(s, 2);                                                     \
      s += __shfl_xor(s, 1);                                                     \
      const float inv = 1.0f / s;                                                \
      float* orow = out + ((size_t)t_g * Bn + b) * Ln;                           \
      store4(orow + 0 * 256 + jx * 4, a##R##_0, inv);                            \
      store4(orow + 1 * 256 + jx * 4, a##R##_1, inv);                            \
      store4(orow + 2 * 256 + jx * 4, a##R##_2, inv);                            \
      store4(orow + 3 * 256 + jx * 4, a##R##_3, inv);                            \
    }                                                                            \
  }

  ROW_EPILOGUE(0)
  ROW_EPILOGUE(1)
  ROW_EPILOGUE(2)
  ROW_EPILOGUE(3)
#undef ROW_EPILOGUE
}

extern "C" void kernel_launch(void* const* d_in, const int* in_sizes, int n_in,
                              void* d_out, int out_size, void* d_ws, size_t ws_size,
                              hipStream_t stream) {
  const float* enc = (const float*)d_in[0];
  const float* W = (const float*)d_in[1];
  const float* bias = (const float*)d_in[2];
  float* out = (float*)d_out;
  float* energy = (float*)d_ws;  // B*L*D floats = 8 MB

  const int Tval = out_size / (Bn * Ln);  // 1024

  energy_kernel<<<dim3(Ln / 4, Bn), 256, 0, stream>>>(enc, W, bias, energy);
  scores_kernel<<<dim3((Tval + TT - 1) / TT, Bn), 256, 0, stream>>>(enc, energy, out, Tval);
}

// Round 8
// 276.177 us; speedup vs baseline: 12.6657x; 12.6087x over previous
//
#include <hip/hip_runtime.h>
#include <hip/hip_bf16.h>

// B=32, L=1024, D=64, T=1024.
// out[t,b,j] = softmax_j( enc[b,t,:] . energy[b,j,:] ), energy = enc@W^T + bias,
// diagonal (j==t) score forced to 0 before softmax.
constexpr int Bn = 32;
constexpr int Ln = 1024;
constexpr int Dn = 64;
constexpr int TT = 8;    // t-rows per block (reduced 16->8 to cut reg pressure)
constexpr int JJ = 256;  // j-tile per LDS stage

// ---------------- Kernel 1: energy[b,l,e] = bias[e] + sum_d enc[b,l,d]*W[e,d] ----------------
__global__ __launch_bounds__(256, 4) void energy_kernel(
    const float* __restrict__ enc, const float* __restrict__ W,
    const float* __restrict__ bias, float* __restrict__ energy) {
  __shared__ float Ws[64 * 64];   // rows e, 16 float4 chunks each, chunk idx XOR (e&15)
  __shared__ float encs[4 * 64];

  const int tid = threadIdx.x;
  const int b = blockIdx.y;
  const int l0 = blockIdx.x * 4;

  const float4* Wsrc = reinterpret_cast<const float4*>(W);
#pragma unroll 2
  for (int s = 0; s < 4; ++s) {
    int f = tid + s * 256;
    int e = f >> 4, d4 = f & 15;
    reinterpret_cast<float4*>(Ws)[e * 16 + (d4 ^ (e & 15))] = Wsrc[f];
  }
  if (tid < 64) {
    reinterpret_cast<float4*>(encs)[tid] =
        reinterpret_cast<const float4*>(enc + ((size_t)b * Ln + l0) * Dn)[tid];
  }
  __syncthreads();

  const int lr = tid >> 6;
  const int e = tid & 63;
  const int x = e & 15;
  float acc = bias[e];
#pragma unroll 4
  for (int d4 = 0; d4 < 16; ++d4) {
    float4 wv = reinterpret_cast<const float4*>(Ws)[e * 16 + (d4 ^ x)];
    float4 ev = reinterpret_cast<const float4*>(encs)[lr * 16 + d4];
    acc += wv.x * ev.x + wv.y * ev.y + wv.z * ev.z + wv.w * ev.w;
  }
  energy[((size_t)b * Ln + l0 + lr) * Dn + e] = acc;
}

// ---------------- Kernel 2 helpers ----------------
__device__ __forceinline__ float dot4(float4 a, float4 b) {
  return a.x * b.x + a.y * b.y + a.z * b.z + a.w * b.w;
}
__device__ __forceinline__ void diagzero(float4& a, int jbase, int t_g) {
  if (jbase + 0 == t_g) a.x = 0.f;
  if (jbase + 1 == t_g) a.y = 0.f;
  if (jbase + 2 == t_g) a.z = 0.f;
  if (jbase + 3 == t_g) a.w = 0.f;
}
__device__ __forceinline__ float max4(float4 a) {
  return fmaxf(fmaxf(a.x, a.y), fmaxf(a.z, a.w));
}
__device__ __forceinline__ float exp4(float4& a, float m) {
  a.x = __expf(a.x - m); a.y = __expf(a.y - m);
  a.z = __expf(a.z - m); a.w = __expf(a.w - m);
  return (a.x + a.y) + (a.z + a.w);
}
__device__ __forceinline__ void store4(float* p, float4 a, float inv) {
  float4 v;
  v.x = a.x * inv; v.y = a.y * inv; v.z = a.z * inv; v.w = a.w * inv;
  *reinterpret_cast<float4*>(p) = v;
}

// ---------------- Kernel 2: scores + diag-zero + softmax + write ----------------
// grid (T/TT, B), block 256 = 4 waves. Wave ty owns 2 t-rows: t0+ty*2+{0,1}.
// Thread (ty,jx): row r, tile T, comp c -> j = T*256 + jx*4 + c.
// Register-pressure budget (the 3.4 ms mystery is suspected acc SPILL at VGPR=128):
//   acc 8 float4 = 32 regs; staging <=4 float4 in flight (chunked, unroll 1);
//   compute operands ~24; addressing ~20  => peak ~95 < 128, no spill expected.
__global__ __launch_bounds__(256, 2) void scores_kernel(
    const float* __restrict__ enc, const float* __restrict__ energy,
    float* __restrict__ out, int Tval) {
  __shared__ float enc_s[TT * Dn];   // 2 KB, linear (wave-broadcast reads)
  __shared__ float eng_s[JJ * Dn];   // 64 KB, float4-chunk XOR-swizzled by (row>>2)&15

  const int tid = threadIdx.x;
  const int b = blockIdx.y;
  const int t0 = blockIdx.x * TT;
  const int ty = tid >> 6;
  const int jx = tid & 63;
  const int x = jx & 15;

  if (tid < TT * (Dn / 4)) {  // 128 float4s
    reinterpret_cast<float4*>(enc_s)[tid] =
        reinterpret_cast<const float4*>(enc + ((size_t)b * Ln + t0) * Dn)[tid];
  }

  float4 a0_0{0,0,0,0}, a0_1{0,0,0,0}, a0_2{0,0,0,0}, a0_3{0,0,0,0};
  float4 a1_0{0,0,0,0}, a1_1{0,0,0,0}, a1_2{0,0,0,0}, a1_3{0,0,0,0};

  const float4* ESF4 = reinterpret_cast<const float4*>(eng_s);
  const float4* ENF4 = reinterpret_cast<const float4*>(enc_s);
  float4* dst = reinterpret_cast<float4*>(eng_s);

#define DO_TILE(JT)                                                              \
  {                                                                              \
    __syncthreads();                                                             \
    const float4* src = reinterpret_cast<const float4*>(                         \
        energy + ((size_t)b * Ln + (JT) * JJ) * Dn);                             \
    _Pragma("unroll 1") for (int s4 = 0; s4 < 4; ++s4) {                         \
      _Pragma("unroll") for (int u = 0; u < 4; ++u) {                            \
        int f = tid + (s4 * 4 + u) * 256;                                        \
        int row = f >> 4, d4c = f & 15;                                          \
        dst[row * 16 + (d4c ^ ((row >> 2) & 15))] = src[f];                      \
      }                                                                          \
    }                                                                            \
    __syncthreads();                                                             \
    _Pragma("unroll 4") for (int d4 = 0; d4 < 16; ++d4) {                        \
      const int d4p = d4 ^ x;                                                    \
      float4 g0 = ESF4[(jx * 4 + 0) * 16 + d4p];                                 \
      float4 g1 = ESF4[(jx * 4 + 1) * 16 + d4p];                                 \
      float4 g2 = ESF4[(jx * 4 + 2) * 16 + d4p];                                 \
      float4 g3 = ESF4[(jx * 4 + 3) * 16 + d4p];                                 \
      float4 e0 = ENF4[(ty * 2 + 0) * 16 + d4];                                  \
      float4 e1 = ENF4[(ty * 2 + 1) * 16 + d4];                                  \
      a0_##JT.x += dot4(e0, g0); a0_##JT.y += dot4(e0, g1);                      \
      a0_##JT.z += dot4(e0, g2); a0_##JT.w += dot4(e0, g3);                      \
      a1_##JT.x += dot4(e1, g0); a1_##JT.y += dot4(e1, g1);                      \
      a1_##JT.z += dot4(e1, g2); a1_##JT.w += dot4(e1, g3);                      \
    }                                                                            \
  }

  DO_TILE(0)
  DO_TILE(1)
  DO_TILE(2)
  DO_TILE(3)
#undef DO_TILE

  // epilogue: per t-row (one wave owns the whole row): diag-zero, softmax, store.
#define ROW_EPILOGUE(R)                                                          \
  {                                                                              \
    const int t_g = t0 + ty * 2 + (R);                                           \
    if (t_g < Tval) {                                                            \
      diagzero(a##R##_0, 0 * 256 + jx * 4, t_g);                                 \
      diagzero(a##R##_1, 1 * 256 + jx * 4, t_g);                                 \
      diagzero(a##R##_2, 2 * 256 + jx * 4, t_g);                                 \
      diagzero(a##R##_3, 3 * 256 + jx * 4, t_g);                                 \
      float m = fmaxf(fmaxf(max4(a##R##_0), max4(a##R##_1)),                     \
                      fmaxf(max4(a##R##_2), max4(a##R##_3)));                    \
      for (int off = 32; off > 0; off >>= 1)                                     \
        m = fmaxf(m, __shfl_xor(m, off));                                        \
      float s = exp4(a##R##_0, m) + exp4(a##R##_1, m) +                          \
                exp4(a##R##_2, m) + exp4(a##R##_3, m);                           \
      for (int off = 32; off > 0; off >>= 1) s += __shfl_xor(s, off);            \
      const float inv = 1.0f / s;                                                \
      float* orow = out + ((size_t)t_g * Bn + b) * Ln;                           \
      store4(orow + 0 * 256 + jx * 4, a##R##_0, inv);                            \
      store4(orow + 1 * 256 + jx * 4, a##R##_1, inv);                            \
      store4(orow + 2 * 256 + jx * 4, a##R##_2, inv);                            \
      store4(orow + 3 * 256 + jx * 4, a##R##_3, inv);                            \
    }                                                                            \
  }

  ROW_EPILOGUE(0)
  ROW_EPILOGUE(1)
#undef ROW_EPILOGUE
}

extern "C" void kernel_launch(void* const* d_in, const int* in_sizes, int n_in,
                              void* d_out, int out_size, void* d_ws, size_t ws_size,
                              hipStream_t stream) {
  const float* enc = (const float*)d_in[0];
  const float* W = (const float*)d_in[1];
  const float* bias = (const float*)d_in[2];
  float* out = (float*)d_out;
  float* energy = (float*)d_ws;  // B*L*D floats = 8 MB

  const int Tval = out_size / (Bn * Ln);  // 1024

  energy_kernel<<<dim3(Ln / 4, Bn), 256, 0, stream>>>(enc, W, bias, energy);
  scores_kernel<<<dim3((Tval + TT - 1) / TT, Bn), 256, 0, stream>>>(enc, energy, out, Tval);
}

// Round 10
// 193.716 us; speedup vs baseline: 18.0573x; 1.4257x over previous
//
#include <hip/hip_runtime.h>
#include <hip/hip_bf16.h>
#include <string.h>

// B=32, L=1024, D=64, T=1024.
// out[t,b,j] = softmax_j( enc[b,t,:] . energy[b,j,:] ), energy = enc@W^T + bias,
// diag (j==t) forced to 0 pre-softmax.
// Strategy: energy kernel emits hi/lo bf16 split planes (3xbf16 fp32-emulation),
// pre-swizzled in global (granule g -> g^(row&7)) so scores kernel stages them
// LINEARLY into LDS and reads MFMA fragments conflict-free (2-way = free).
constexpr int Bn = 32;
constexpr int Ln = 1024;
constexpr int Dn = 64;
constexpr int TM = 16;   // t-rows per scores block
constexpr int JJ = 256;  // j-panel per LDS stage

typedef __attribute__((ext_vector_type(4))) float f32x4;
typedef __attribute__((ext_vector_type(8))) short short8;

__device__ __forceinline__ ushort bf16_bits(float x) {
  __hip_bfloat16 h = __float2bfloat16(x);
  ushort u; memcpy(&u, &h, 2); return u;
}
__device__ __forceinline__ float bf16_round(float x) {
  return __bfloat162float(__float2bfloat16(x));
}
__device__ __forceinline__ float dot4f(float4 a, float4 b) {
  return a.x * b.x + a.y * b.y + a.z * b.z + a.w * b.w;
}

// ---------------- Kernel 1: energy -> hi/lo bf16 planes, swizzled ----------------
// grid (L/32, B), block 256. Wave lane = e (64 features); lr=tid>>6; rows lr+4k.
__global__ __launch_bounds__(256, 4) void energy_kernel(
    const float* __restrict__ enc, const float* __restrict__ W,
    const float* __restrict__ bias, ushort* __restrict__ ehi,
    ushort* __restrict__ elo) {
  __shared__ float Ws[64 * 64];    // [e][16 f4 chunks], chunk idx XOR (e&15)
  __shared__ float encs[32 * 64];  // 32 rows linear

  const int tid = threadIdx.x;
  const int b = blockIdx.y;
  const int l0 = blockIdx.x * 32;

  const float4* Wsrc = reinterpret_cast<const float4*>(W);
  float4* Wds = reinterpret_cast<float4*>(Ws);
#pragma unroll
  for (int s = 0; s < 4; ++s) {
    int f = tid + s * 256;
    int e = f >> 4, d4 = f & 15;
    Wds[e * 16 + (d4 ^ (e & 15))] = Wsrc[f];
  }
  const float4* esrc = reinterpret_cast<const float4*>(enc + ((size_t)b * Ln + l0) * Dn);
  float4* eds = reinterpret_cast<float4*>(encs);
#pragma unroll
  for (int s = 0; s < 2; ++s) eds[tid + s * 256] = esrc[tid + s * 256];
  __syncthreads();

  const int lr = tid >> 6;  // 0..3
  const int e = tid & 63;
  const int x = e & 15;
  float a0 = 0, a1 = 0, a2 = 0, a3 = 0, a4 = 0, a5 = 0, a6 = 0, a7 = 0;
  const float4* WF = reinterpret_cast<const float4*>(Ws);
  const float4* EF = reinterpret_cast<const float4*>(encs);
#pragma unroll 4
  for (int d4 = 0; d4 < 16; ++d4) {
    float4 wv = WF[e * 16 + (d4 ^ x)];
    a0 += dot4f(wv, EF[(lr + 0) * 16 + d4]);
    a1 += dot4f(wv, EF[(lr + 4) * 16 + d4]);
    a2 += dot4f(wv, EF[(lr + 8) * 16 + d4]);
    a3 += dot4f(wv, EF[(lr + 12) * 16 + d4]);
    a4 += dot4f(wv, EF[(lr + 16) * 16 + d4]);
    a5 += dot4f(wv, EF[(lr + 20) * 16 + d4]);
    a6 += dot4f(wv, EF[(lr + 24) * 16 + d4]);
    a7 += dot4f(wv, EF[(lr + 28) * 16 + d4]);
  }
  const float bv = bias[e];
  const int g = e >> 3, ew = e & 7;
#define EMIT(K, ACC)                                              \
  {                                                               \
    int row = l0 + lr + 4 * (K);                                  \
    float xv = (ACC) + bv;                                        \
    float hf = bf16_round(xv);                                    \
    size_t base = ((size_t)b * Ln + row) * 64;                    \
    int slot = g ^ (row & 7);                                     \
    ehi[base + slot * 8 + ew] = bf16_bits(xv);                    \
    elo[base + slot * 8 + ew] = bf16_bits(xv - hf);               \
  }
  EMIT(0, a0) EMIT(1, a1) EMIT(2, a2) EMIT(3, a3)
  EMIT(4, a4) EMIT(5, a5) EMIT(6, a6) EMIT(7, a7)
#undef EMIT
}

// ---------------- Kernel 2: MFMA scores + diag-zero + softmax + write ----------------
// grid (ceil(T/16), B), block 256 = 4 waves. Block: 16 t-rows x full 1024 j.
// Wave w owns panel-local j [w*64, w*64+64) over 4 panels -> 16 16x16 C tiles.
// MFMA 16x16x32 bf16, 3-term hi/lo split (drop lo*lo).
// A frag: row=l&15, k=(l>>4)*8+e. B frag: col=l&15, k=(l>>4)*8+e.
// C frag: col=l&15, row=(l>>4)*4+reg (m89-verified).
__global__ __launch_bounds__(256, 2) void scores_kernel(
    const float* __restrict__ enc, const ushort* __restrict__ ehi,
    const ushort* __restrict__ elo, float* __restrict__ out, int Tval) {
  __shared__ ushort Eh[JJ * Dn];  // 32 KB, swizzled (slot = g ^ (row&7))
  __shared__ ushort El[JJ * Dn];  // 32 KB
  __shared__ ushort Ahs[TM * Dn]; // 2 KB
  __shared__ ushort Als[TM * Dn]; // 2 KB
  __shared__ float rmax[TM][4];
  __shared__ float rsum[TM][4];

  const int tid = threadIdx.x;
  const int b = blockIdx.y;
  const int t0 = blockIdx.x * TM;
  const int w = tid >> 6;
  const int l = tid & 63;
  const int l15 = l & 15, lh = l >> 4, key = l & 7;

  // enc tile -> hi/lo bf16, swizzled into LDS. 256 threads = 16 rows x 16 f4.
  {
    int row = tid >> 4, d4 = tid & 15;
    int rg = t0 + row; if (rg >= Ln) rg = Ln - 1;
    float4 v = reinterpret_cast<const float4*>(enc + ((size_t)b * Ln + rg) * Dn)[d4];
    float hx = bf16_round(v.x), hy = bf16_round(v.y), hz = bf16_round(v.z), hw = bf16_round(v.w);
    uint2 hp, lp;
    hp.x = (uint)bf16_bits(v.x) | ((uint)bf16_bits(v.y) << 16);
    hp.y = (uint)bf16_bits(v.z) | ((uint)bf16_bits(v.w) << 16);
    lp.x = (uint)bf16_bits(v.x - hx) | ((uint)bf16_bits(v.y - hy) << 16);
    lp.y = (uint)bf16_bits(v.z - hz) | ((uint)bf16_bits(v.w - hw) << 16);
    int idx = row * 64 + ((d4 >> 1) ^ (row & 7)) * 8 + (d4 & 1) * 4;
    *reinterpret_cast<uint2*>(&Ahs[idx]) = hp;
    *reinterpret_cast<uint2*>(&Als[idx]) = lp;
  }

  f32x4 c0_0 = {0,0,0,0}, c0_1 = {0,0,0,0}, c0_2 = {0,0,0,0}, c0_3 = {0,0,0,0};
  f32x4 c1_0 = {0,0,0,0}, c1_1 = {0,0,0,0}, c1_2 = {0,0,0,0}, c1_3 = {0,0,0,0};
  f32x4 c2_0 = {0,0,0,0}, c2_1 = {0,0,0,0}, c2_2 = {0,0,0,0}, c2_3 = {0,0,0,0};
  f32x4 c3_0 = {0,0,0,0}, c3_1 = {0,0,0,0}, c3_2 = {0,0,0,0}, c3_3 = {0,0,0,0};
  short8 ah0, ah1, am0, am1;  // A hi (k-chunk 0/1), A lo (k-chunk 0/1)

#define TILE(JP, JT)                                                            \
  {                                                                             \
    const int rb = ((w) * 64 + (JT) * 16 + l15) * 64;                           \
    short8 bh0 = *reinterpret_cast<const short8*>(&Eh[rb + ((lh) ^ key) * 8]);  \
    short8 bh1 = *reinterpret_cast<const short8*>(&Eh[rb + ((4 + lh) ^ key) * 8]); \
    short8 bl0 = *reinterpret_cast<const short8*>(&El[rb + ((lh) ^ key) * 8]);  \
    short8 bl1 = *reinterpret_cast<const short8*>(&El[rb + ((4 + lh) ^ key) * 8]); \
    c##JP##_##JT = __builtin_amdgcn_mfma_f32_16x16x32_bf16(ah0, bh0, c##JP##_##JT, 0, 0, 0); \
    c##JP##_##JT = __builtin_amdgcn_mfma_f32_16x16x32_bf16(ah1, bh1, c##JP##_##JT, 0, 0, 0); \
    c##JP##_##JT = __builtin_amdgcn_mfma_f32_16x16x32_bf16(am0, bh0, c##JP##_##JT, 0, 0, 0); \
    c##JP##_##JT = __builtin_amdgcn_mfma_f32_16x16x32_bf16(am1, bh1, c##JP##_##JT, 0, 0, 0); \
    c##JP##_##JT = __builtin_amdgcn_mfma_f32_16x16x32_bf16(ah0, bl0, c##JP##_##JT, 0, 0, 0); \
    c##JP##_##JT = __builtin_amdgcn_mfma_f32_16x16x32_bf16(ah1, bl1, c##JP##_##JT, 0, 0, 0); \
  }

#define PHASE(JP, LOADA)                                                        \
  {                                                                             \
    __syncthreads();                                                            \
    const uint4* hs = reinterpret_cast<const uint4*>(ehi + ((size_t)b * Ln + (JP) * JJ) * Dn); \
    const uint4* ls = reinterpret_cast<const uint4*>(elo + ((size_t)b * Ln + (JP) * JJ) * Dn); \
    uint4* hd = reinterpret_cast<uint4*>(Eh);                                   \
    uint4* ld2 = reinterpret_cast<uint4*>(El);                                  \
    _Pragma("unroll 4") for (int i = 0; i < 8; ++i) hd[tid + i * 256] = hs[tid + i * 256]; \
    _Pragma("unroll 4") for (int i = 0; i < 8; ++i) ld2[tid + i * 256] = ls[tid + i * 256]; \
    __syncthreads();                                                            \
    if (LOADA) {                                                                \
      ah0 = *reinterpret_cast<const short8*>(&Ahs[l15 * 64 + ((lh) ^ key) * 8]);      \
      ah1 = *reinterpret_cast<const short8*>(&Ahs[l15 * 64 + ((4 + lh) ^ key) * 8]);  \
      am0 = *reinterpret_cast<const short8*>(&Als[l15 * 64 + ((lh) ^ key) * 8]);      \
      am1 = *reinterpret_cast<const short8*>(&Als[l15 * 64 + ((4 + lh) ^ key) * 8]);  \
    }                                                                           \
    TILE(JP, 0) TILE(JP, 1) TILE(JP, 2) TILE(JP, 3)                             \
  }

  PHASE(0, 1)
  PHASE(1, 0)
  PHASE(2, 0)
  PHASE(3, 0)
#undef PHASE
#undef TILE

  // ---- epilogue: diag-zero, block softmax over j, scale, store ----
  const int r0 = lh * 4;
  float m0 = -1e30f, m1 = -1e30f, m2 = -1e30f, m3 = -1e30f;
#define DIAGMAX(JP, JT)                                           \
  {                                                               \
    int j = (JP) * 256 + w * 64 + (JT) * 16 + l15;                \
    f32x4& C = c##JP##_##JT;                                      \
    C.x = (j == t0 + r0 + 0) ? 0.f : C.x;                         \
    C.y = (j == t0 + r0 + 1) ? 0.f : C.y;                         \
    C.z = (j == t0 + r0 + 2) ? 0.f : C.z;                         \
    C.w = (j == t0 + r0 + 3) ? 0.f : C.w;                         \
    m0 = fmaxf(m0, C.x); m1 = fmaxf(m1, C.y);                     \
    m2 = fmaxf(m2, C.z); m3 = fmaxf(m3, C.w);                     \
  }
  DIAGMAX(0, 0) DIAGMAX(0, 1) DIAGMAX(0, 2) DIAGMAX(0, 3)
  DIAGMAX(1, 0) DIAGMAX(1, 1) DIAGMAX(1, 2) DIAGMAX(1, 3)
  DIAGMAX(2, 0) DIAGMAX(2, 1) DIAGMAX(2, 2) DIAGMAX(2, 3)
  DIAGMAX(3, 0) DIAGMAX(3, 1) DIAGMAX(3, 2) DIAGMAX(3, 3)
#undef DIAGMAX
#pragma unroll
  for (int off = 1; off < 16; off <<= 1) {
    m0 = fmaxf(m0, __shfl_xor(m0, off));
    m1 = fmaxf(m1, __shfl_xor(m1, off));
    m2 = fmaxf(m2, __shfl_xor(m2, off));
    m3 = fmaxf(m3, __shfl_xor(m3, off));
  }
  if (l15 == 0) {
    rmax[r0 + 0][w] = m0; rmax[r0 + 1][w] = m1;
    rmax[r0 + 2][w] = m2; rmax[r0 + 3][w] = m3;
  }
  __syncthreads();
  m0 = fmaxf(fmaxf(rmax[r0 + 0][0], rmax[r0 + 0][1]), fmaxf(rmax[r0 + 0][2], rmax[r0 + 0][3]));
  m1 = fmaxf(fmaxf(rmax[r0 + 1][0], rmax[r0 + 1][1]), fmaxf(rmax[r0 + 1][2], rmax[r0 + 1][3]));
  m2 = fmaxf(fmaxf(rmax[r0 + 2][0], rmax[r0 + 2][1]), fmaxf(rmax[r0 + 2][2], rmax[r0 + 2][3]));
  m3 = fmaxf(fmaxf(rmax[r0 + 3][0], rmax[r0 + 3][1]), fmaxf(rmax[r0 + 3][2], rmax[r0 + 3][3]));
  float s0 = 0.f, s1 = 0.f, s2 = 0.f, s3 = 0.f;
#define EXPSUM(JP, JT)                                            \
  {                                                               \
    f32x4& C = c##JP##_##JT;                                      \
    C.x = __expf(C.x - m0); s0 += C.x;                            \
    C.y = __expf(C.y - m1); s1 += C.y;                            \
    C.z = __expf(C.z - m2); s2 += C.z;                            \
    C.w = __expf(C.w - m3); s3 += C.w;                            \
  }
  EXPSUM(0, 0) EXPSUM(0, 1) EXPSUM(0, 2) EXPSUM(0, 3)
  EXPSUM(1, 0) EXPSUM(1, 1) EXPSUM(1, 2) EXPSUM(1, 3)
  EXPSUM(2, 0) EXPSUM(2, 1) EXPSUM(2, 2) EXPSUM(2, 3)
  EXPSUM(3, 0) EXPSUM(3, 1) EXPSUM(3, 2) EXPSUM(3, 3)
#undef EXPSUM
#pragma unroll
  for (int off = 1; off < 16; off <<= 1) {
    s0 += __shfl_xor(s0, off);
    s1 += __shfl_xor(s1, off);
    s2 += __shfl_xor(s2, off);
    s3 += __shfl_xor(s3, off);
  }
  if (l15 == 0) {
    rsum[r0 + 0][w] = s0; rsum[r0 + 1][w] = s1;
    rsum[r0 + 2][w] = s2; rsum[r0 + 3][w] = s3;
  }
  __syncthreads();
  const float i0 = 1.0f / (rsum[r0 + 0][0] + rsum[r0 + 0][1] + rsum[r0 + 0][2] + rsum[r0 + 0][3]);
  const float i1 = 1.0f / (rsum[r0 + 1][0] + rsum[r0 + 1][1] + rsum[r0 + 1][2] + rsum[r0 + 1][3]);
  const float i2 = 1.0f / (rsum[r0 + 2][0] + rsum[r0 + 2][1] + rsum[r0 + 2][2] + rsum[r0 + 2][3]);
  const float i3 = 1.0f / (rsum[r0 + 3][0] + rsum[r0 + 3][1] + rsum[r0 + 3][2] + rsum[r0 + 3][3]);
#define STORE(JP, JT)                                                           \
  {                                                                             \
    int j = (JP) * 256 + w * 64 + (JT) * 16 + l15;                              \
    f32x4& C = c##JP##_##JT;                                                    \
    if (t0 + r0 + 0 < Tval) out[((size_t)(t0 + r0 + 0) * Bn + b) * Ln + j] = C.x * i0; \
    if (t0 + r0 + 1 < Tval) out[((size_t)(t0 + r0 + 1) * Bn + b) * Ln + j] = C.y * i1; \
    if (t0 + r0 + 2 < Tval) out[((size_t)(t0 + r0 + 2) * Bn + b) * Ln + j] = C.z * i2; \
    if (t0 + r0 + 3 < Tval) out[((size_t)(t0 + r0 + 3) * Bn + b) * Ln + j] = C.w * i3; \
  }
  STORE(0, 0) STORE(0, 1) STORE(0, 2) STORE(0, 3)
  STORE(1, 0) STORE(1, 1) STORE(1, 2) STORE(1, 3)
  STORE(2, 0) STORE(2, 1) STORE(2, 2) STORE(2, 3)
  STORE(3, 0) STORE(3, 1) STORE(3, 2) STORE(3, 3)
#undef STORE
}

extern "C" void kernel_launch(void* const* d_in, const int* in_sizes, int n_in,
                              void* d_out, int out_size, void* d_ws, size_t ws_size,
                              hipStream_t stream) {
  const float* enc = (const float*)d_in[0];
  const float* W = (const float*)d_in[1];
  const float* bias = (const float*)d_in[2];
  float* out = (float*)d_out;
  ushort* ehi = (ushort*)d_ws;                       // 4 MB
  ushort* elo = ehi + (size_t)Bn * Ln * Dn;          // 4 MB

  const int Tval = out_size / (Bn * Ln);  // 1024

  energy_kernel<<<dim3(Ln / 32, Bn), 256, 0, stream>>>(enc, W, bias, ehi, elo);
  scores_kernel<<<dim3((Tval + TM - 1) / TM, Bn), 256, 0, stream>>>(enc, ehi, elo, out, Tval);
}